// Round 5
// baseline (521.820 us; speedup 1.0000x reference)
//
#include <hip/hip_runtime.h>
#include <cstdint>
#include <cstddef>

// ---------- types ----------
typedef __attribute__((ext_vector_type(8))) short short8;        // MFMA bf16 A/B frag (4 VGPR)
typedef __attribute__((ext_vector_type(4))) float f32x4;         // MFMA C/D frag
typedef __attribute__((ext_vector_type(4))) unsigned short ushort4_t;

// RNE float->bf16 (finite inputs only)
__device__ __forceinline__ unsigned short f2bf(float f) {
  unsigned u = __float_as_uint(f);
  u += 0x7FFFu + ((u >> 16) & 1u);
  return (unsigned short)(u >> 16);
}

// async global->LDS, 16B per lane. LDS dest is wave-uniform base (+lane*16 implicit).
__device__ __forceinline__ void gload_lds16(const void* g, void* lds) {
  __builtin_amdgcn_global_load_lds((const __attribute__((address_space(1))) void*)g,
                                   (__attribute__((address_space(3))) void*)lds,
                                   16, 0, 0);
}

// Branch-free erf (A&S 7.1.26, abs err <= 1.5e-7), sign folded via bit ops.
__device__ __forceinline__ float erf_fast(float v) {
  float x = fabsf(v);
  float t = __builtin_amdgcn_rcpf(fmaf(0.3275911f, x, 1.0f));
  float p = fmaf(1.061405429f, t, -1.453152027f);
  p = fmaf(p, t, 1.421413741f);
  p = fmaf(p, t, -0.284496736f);
  p = fmaf(p, t, 0.254829592f);
  p = p * t;
  float e = fmaf(-p, __expf(-x * x), 1.0f);      // erf(|v|), >= 0
  unsigned s = __float_as_uint(v) & 0x80000000u;
  return __uint_as_float(__float_as_uint(e) | s);
}

// ---------- kernel 1: quantize x with per-channel s_a1 (symmetric, qn=-128 qp=127) ----------
__global__ void quant_x_kernel(const float4* __restrict__ x, const float* __restrict__ s_a1,
                               ushort4_t* __restrict__ xq, int n4, int c4mask) {
  const int stride = gridDim.x * blockDim.x;
  for (int i = blockIdx.x * blockDim.x + threadIdx.x; i < n4; i += stride) {
    float4 v = x[i];
    int c = (i & c4mask) << 2;           // channel base (C is pow2)
    float vv[4] = {v.x, v.y, v.z, v.w};
    ushort4_t o;
#pragma unroll
    for (int j = 0; j < 4; ++j) {
      float s = s_a1[c + j];
      float r = vv[j] / s;
      r = fminf(fmaxf(r, -128.f), 127.f);
      o[j] = f2bf(rintf(r) * s);
    }
    xq[i] = o;
  }
}

// ---------- kernel 2: statsq weight quant, one block (256 thr) per output row ----------
__global__ void quant_w_kernel(const float* __restrict__ w, unsigned short* __restrict__ wq,
                               int cols) {
  const int row = blockIdx.x;
  const float* wr = w + (size_t)row * cols;
  float part = 0.f;
  for (int j = threadIdx.x; j < cols; j += blockDim.x) part += fabsf(wr[j]);
#pragma unroll
  for (int o = 32; o > 0; o >>= 1) part += __shfl_down(part, o, 64);
  __shared__ float wsum[4];
  if ((threadIdx.x & 63) == 0) wsum[threadIdx.x >> 6] = part;
  __syncthreads();
  float mean = (wsum[0] + wsum[1] + wsum[2] + wsum[3]) / (float)cols;
  float s = 2.f * mean / sqrtf(127.f);
  unsigned short* wqr = wq + (size_t)row * cols;
  for (int j = threadIdx.x; j < cols; j += blockDim.x) {
    float r = wr[j] / s;
    r = fminf(fmaxf(r, -128.f), 127.f);
    wqr[j] = f2bf(rintf(r) * s);
  }
}

// ---------- pipelined 256x256 GEMM (A: MxK rm, B: NxK rm), gray-coded quadrants ----------
// Per-tile: 1 barrier, placed after Q2 so Q3+Q4 (1240cy MFMA) cover the post-BAR
// stage issue + next-tile entry reads. Quadrant order gray-coded with even/odd
// register-role rotation so entry reads split: B-half(4) post-BAR, A-half(8) post-Q3,
// each WAR-anchored after its last consumer. Counted lgkm waits (8/4/0); vmcnt(0)
// only proves stages issued a full tile earlier (~free). Race audit:
//  - cur-buf ds_reads all drained at LGKM(0) before BAR -> STG(cur) post-BAR safe.
//  - next-buf reads: after own VMC0 (asm memory clobber anchors) + BAR + SB.
//  - every pre-read target register is dead (program-order after last MFMA use).
#define BAR() __builtin_amdgcn_s_barrier()
#define SB() __builtin_amdgcn_sched_barrier(0)
#define LGKM(n) { asm volatile("s_waitcnt lgkmcnt(" #n ")" ::: "memory"); SB(); }
#define VMC0() { asm volatile("s_waitcnt vmcnt(0)" ::: "memory"); SB(); }
#define PRIO1() __builtin_amdgcn_s_setprio(1)
#define PRIO0() __builtin_amdgcn_s_setprio(0)

#define STG(gbase, ldsbuf, h, kt) { \
  _Pragma("unroll") for (int i_ = 0; i_ < 2; ++i_) { \
    const int rb_ = (h) * 128 + (w * 2 + i_) * 8; \
    gload_lds16((gbase) + (size_t)rb_ * K + (size_t)(kt) * 64, (void*)((ldsbuf) + rb_ * 64)); } }

#define LDA_(dst, buf, mh) { \
  _Pragma("unroll") for (int mi_ = 0; mi_ < 4; ++mi_) { \
    dst[mi_][0] = *(const short8*)((buf) + aBase + (mh) * 4096 + mi_ * 1024 + ck0); \
    dst[mi_][1] = *(const short8*)((buf) + aBase + (mh) * 4096 + mi_ * 1024 + ck1); } }

#define LDB_(dst, buf, nh) { \
  _Pragma("unroll") for (int ni_ = 0; ni_ < 2; ++ni_) { \
    dst[ni_][0] = *(const short8*)((buf) + bBase + (nh) * 2048 + ni_ * 1024 + ck0); \
    dst[ni_][1] = *(const short8*)((buf) + bBase + (nh) * 2048 + ni_ * 1024 + ck1); } }

#define MMQ(aR, bR, mh, nh) { \
  _Pragma("unroll") for (int kk_ = 0; kk_ < 2; ++kk_) \
  _Pragma("unroll") for (int mi_ = 0; mi_ < 4; ++mi_) \
  _Pragma("unroll") for (int ni_ = 0; ni_ < 2; ++ni_) \
    acc[(mh) * 4 + mi_][(nh) * 2 + ni_] = __builtin_amdgcn_mfma_f32_16x16x32_bf16( \
        aR[mi_][kk_], bR[ni_][kk_], acc[(mh) * 4 + mi_][(nh) * 2 + ni_], 0, 0, 0); }

template <int EPI>
__global__ __launch_bounds__(512, 2) void gemm_bt_gc(
    const unsigned short* __restrict__ A, const unsigned short* __restrict__ B,
    const float* __restrict__ bias, const float* __restrict__ s2,
    const float* __restrict__ beta, unsigned short* __restrict__ Cq,
    float* __restrict__ Cf, int N, int K)
{
  __shared__ __align__(16) unsigned short As0[256 * 64];
  __shared__ __align__(16) unsigned short As1[256 * 64];
  __shared__ __align__(16) unsigned short Bs0[256 * 64];
  __shared__ __align__(16) unsigned short Bs1[256 * 64];

  const int tid = threadIdx.x;
  const int w = tid >> 6, ll = tid & 63;
  const int wr = w >> 2, wc = w & 3;
  const long bm = (long)blockIdx.x * 256;
  const long bn = (long)blockIdx.y * 256;

  // staging source (pre-swizzled so linear LDS dest + XOR read = consistent, rule #21)
  const int srow = ll >> 3;
  const int scol = ((ll & 7) ^ srow) << 3;
  const unsigned short* Agl = A + ((size_t)bm + srow) * K + scol;
  const unsigned short* Bgl = B + ((size_t)bn + srow) * K + scol;

  // per-lane ds_read offsets (u16 elems)
  const int lhi = ll >> 4, llo = ll & 15, l7 = ll & 7;
  const int ck0 = ((0 * 4 + lhi) ^ l7) * 8;
  const int ck1 = ((1 * 4 + lhi) ^ l7) * 8;
  const int aBase = (wr * 128 + llo) * 64;
  const int bBase = (wc * 64 + llo) * 64;

  f32x4 acc[8][4] = {};
  short8 pa0[4][2], pa1[4][2], pb0[2][2], pb1[2][2];

  const int nkt = K >> 6;   // even, >= 2 for all shapes here

  // ---- prologue: stage tile0 -> buf0, tile1 -> buf1; prove tile0; entry reads ----
  STG(Agl, As0, 0, 0); STG(Agl, As0, 1, 0);
  STG(Bgl, Bs0, 0, 0); STG(Bgl, Bs0, 1, 0);
  STG(Agl, As1, 0, 1); STG(Agl, As1, 1, 1);
  STG(Bgl, Bs1, 0, 1); STG(Bgl, Bs1, 1, 1);
  asm volatile("s_waitcnt vmcnt(8)" ::: "memory"); SB();
  BAR(); SB();
  LDB_(pb0, Bs0, 0);                 // entry B-half0 (4 reads, oldest)
  LDA_(pa0, As0, 0);                 // entry A-half0 (8 reads)

  for (int t = 0; t < nkt; t += 2) {
    // ================= EVEN tile t: cur=As0/Bs0, next=As1/Bs1 =================
    {
      const bool s2a = (t + 2 < nkt);
      LDA_(pa1, As0, 1);                                // in-tile A-half1 (+8 -> 20)
      LGKM(8);                                          // entry(12) done
      PRIO1(); MMQ(pa0, pb0, 0, 0); PRIO0();            // Q1 (0,0)
      LDB_(pb1, Bs0, 1);                                // in-tile B-half1 (+4)
      LGKM(4);                                          // pa1 done
      PRIO1(); MMQ(pa1, pb0, 1, 0); PRIO0();            // Q2 (1,0)
      LGKM(0);                                          // pb1 done; all cur reads drained
      VMC0();                                           // t+1 stages landed (own)
      BAR(); SB();                                      // block-wide proof; cur free
      if (s2a) { STG(Agl, As0, 0, t + 2); STG(Agl, As0, 1, t + 2);
                 STG(Bgl, Bs0, 0, t + 2); STG(Bgl, Bs0, 1, t + 2); }
      LDB_(pb0, Bs1, 0);                                // entry B(t+1) (pb0 dead after Q2)
      PRIO1(); MMQ(pa1, pb1, 1, 1); PRIO0();            // Q3 (1,1)
      LDA_(pa1, As1, 1);                                // entry A(t+1) (pa1 dead after Q3)
      PRIO1(); MMQ(pa0, pb1, 0, 1); PRIO0();            // Q4 (0,1)
    }
    // ================= ODD tile t+1: cur=As1/Bs1, next=As0/Bs0 =================
    {
      const int to = t + 1;
      const bool cont = (to + 1 < nkt);
      const bool s3 = (to + 2 < nkt);
      LDA_(pa0, As1, 0);                                // in-tile A-half0 (+8 -> 20)
      LGKM(8);                                          // entry(12) done
      PRIO1(); MMQ(pa1, pb0, 1, 0); PRIO0();            // Q1 (1,0)
      LDB_(pb1, Bs1, 1);                                // in-tile B-half1 (+4)
      LGKM(4);                                          // pa0 done
      PRIO1(); MMQ(pa0, pb0, 0, 0); PRIO0();            // Q2 (0,0)
      LGKM(0);                                          // pb1 done
      VMC0();
      BAR(); SB();
      if (s3) { STG(Agl, As1, 0, to + 2); STG(Agl, As1, 1, to + 2);
                STG(Bgl, Bs1, 0, to + 2); STG(Bgl, Bs1, 1, to + 2); }
      if (cont) LDB_(pb0, Bs0, 0);                      // entry B(t+2)
      PRIO1(); MMQ(pa0, pb1, 0, 1); PRIO0();            // Q3 (0,1)
      if (cont) LDA_(pa0, As0, 0);                      // entry A(t+2)
      PRIO1(); MMQ(pa1, pb1, 1, 1); PRIO0();            // Q4 (1,1)
    }
  }

  // ---- epilogue; C/D layout: col = lane&15, row = (lane>>4)*4 + reg ----
  // Row-major store order (MI,r outer; NI inner) -> each row's 64 consecutive
  // cols land temporally together => full-line write combining in L2.
  const int lr = lhi;
  const int lc = llo;
  float bv[4], sv[4], bev[4], inv[4];
#pragma unroll
  for (int NI = 0; NI < 4; ++NI) {
    const long col = bn + wc * 64 + NI * 16 + lc;
    bv[NI] = bias[col];
    if (EPI == 0) { sv[NI] = s2[col]; bev[NI] = beta[col]; inv[NI] = 1.0f / sv[NI]; }
    else { sv[NI] = 1.f; bev[NI] = 0.f; inv[NI] = 1.f; }
  }
  const long colb = bn + wc * 64 + lc;
#pragma unroll
  for (int MI = 0; MI < 8; ++MI) {
#pragma unroll
    for (int r = 0; r < 4; ++r) {
      const size_t rowg = (size_t)(bm + wr * 128 + MI * 16 + lr * 4 + r);
#pragma unroll
      for (int NI = 0; NI < 4; ++NI) {
        float v = acc[MI][NI][r] + bv[NI];
        if (EPI == 0) {
          float g = 0.5f * v * (1.f + erf_fast(v * 0.70710678118654752f));
          float rr = (g - bev[NI]) * inv[NI];
          rr = fminf(fmaxf(rr, 0.f), 255.f);
          Cq[rowg * N + colb + NI * 16] = f2bf(fmaf(rintf(rr), sv[NI], bev[NI]));
        } else {
          Cf[rowg * N + colb + NI * 16] = v;
        }
      }
    }
  }
}

// ---------- launch ----------
extern "C" void kernel_launch(void* const* d_in, const int* in_sizes, int n_in,
                              void* d_out, int out_size, void* d_ws, size_t ws_size,
                              hipStream_t stream) {
  const float* x     = (const float*)d_in[0];
  const float* w1    = (const float*)d_in[1];
  const float* b1    = (const float*)d_in[2];
  const float* w2    = (const float*)d_in[3];
  const float* b2    = (const float*)d_in[4];
  const float* s_a1  = (const float*)d_in[5];
  const float* s_a2  = (const float*)d_in[6];
  const float* beta2 = (const float*)d_in[7];
  float* out = (float*)d_out;

  const int C = 1024, H = 4096;
  const int M = in_sizes[0] / C;  // 16384

  // workspace layout (bf16 bit-patterns as u16): xq | wq1 | wq2 | hq
  unsigned short* xq  = (unsigned short*)d_ws;
  unsigned short* wq1 = xq  + (size_t)M * C;
  unsigned short* wq2 = wq1 + (size_t)H * C;
  unsigned short* hq  = wq2 + (size_t)C * H;

  quant_x_kernel<<<2048, 256, 0, stream>>>((const float4*)x, s_a1, (ushort4_t*)xq,
                                           M * C / 4, C / 4 - 1);
  quant_w_kernel<<<H, 256, 0, stream>>>(w1, wq1, C);
  quant_w_kernel<<<C, 256, 0, stream>>>(w2, wq2, H);

  dim3 g1(M / 256, H / 256);  // 64 x 16
  gemm_bt_gc<0><<<g1, 512, 0, stream>>>(xq, wq1, b1, s_a2, beta2, hq, nullptr, H, C);
  dim3 g2(M / 256, C / 256);  // 64 x 4
  gemm_bt_gc<1><<<g2, 512, 0, stream>>>(hq, wq2, b2, nullptr, nullptr, nullptr, out, C, H);
}

// Round 6
// 356.660 us; speedup vs baseline: 1.4631x; 1.4631x over previous
//
#include <hip/hip_runtime.h>
#include <cstdint>
#include <cstddef>

// ---------- types ----------
typedef __attribute__((ext_vector_type(8))) short short8;        // MFMA bf16 A/B frag (4 VGPR)
typedef __attribute__((ext_vector_type(4))) float f32x4;         // MFMA C/D frag
typedef __attribute__((ext_vector_type(4))) unsigned short ushort4_t;

// RNE float->bf16 (finite inputs only)
__device__ __forceinline__ unsigned short f2bf(float f) {
  unsigned u = __float_as_uint(f);
  u += 0x7FFFu + ((u >> 16) & 1u);
  return (unsigned short)(u >> 16);
}

// async global->LDS, 16B per lane. LDS dest is wave-uniform base (+lane*16 implicit).
__device__ __forceinline__ void gload_lds16(const void* g, void* lds) {
  __builtin_amdgcn_global_load_lds((const __attribute__((address_space(1))) void*)g,
                                   (__attribute__((address_space(3))) void*)lds,
                                   16, 0, 0);
}

// Branch-free erf (A&S 7.1.26, abs err <= 1.5e-7), sign folded via bit ops.
__device__ __forceinline__ float erf_fast(float v) {
  float x = fabsf(v);
  float t = __builtin_amdgcn_rcpf(fmaf(0.3275911f, x, 1.0f));
  float p = fmaf(1.061405429f, t, -1.453152027f);
  p = fmaf(p, t, 1.421413741f);
  p = fmaf(p, t, -0.284496736f);
  p = fmaf(p, t, 0.254829592f);
  p = p * t;
  float e = fmaf(-p, __expf(-x * x), 1.0f);      // erf(|v|), >= 0
  unsigned s = __float_as_uint(v) & 0x80000000u;
  return __uint_as_float(__float_as_uint(e) | s);
}

// ---------- kernel 1: quantize x with per-channel s_a1 (symmetric, qn=-128 qp=127) ----------
__global__ void quant_x_kernel(const float4* __restrict__ x, const float* __restrict__ s_a1,
                               ushort4_t* __restrict__ xq, int n4, int c4mask) {
  const int stride = gridDim.x * blockDim.x;
  for (int i = blockIdx.x * blockDim.x + threadIdx.x; i < n4; i += stride) {
    float4 v = x[i];
    int c = (i & c4mask) << 2;           // channel base (C is pow2)
    float vv[4] = {v.x, v.y, v.z, v.w};
    ushort4_t o;
#pragma unroll
    for (int j = 0; j < 4; ++j) {
      float s = s_a1[c + j];
      float r = vv[j] / s;
      r = fminf(fmaxf(r, -128.f), 127.f);
      o[j] = f2bf(rintf(r) * s);
    }
    xq[i] = o;
  }
}

// ---------- kernel 2: statsq weight quant, one block (256 thr) per output row ----------
__global__ void quant_w_kernel(const float* __restrict__ w, unsigned short* __restrict__ wq,
                               int cols) {
  const int row = blockIdx.x;
  const float* wr = w + (size_t)row * cols;
  float part = 0.f;
  for (int j = threadIdx.x; j < cols; j += blockDim.x) part += fabsf(wr[j]);
#pragma unroll
  for (int o = 32; o > 0; o >>= 1) part += __shfl_down(part, o, 64);
  __shared__ float wsum[4];
  if ((threadIdx.x & 63) == 0) wsum[threadIdx.x >> 6] = part;
  __syncthreads();
  float mean = (wsum[0] + wsum[1] + wsum[2] + wsum[3]) / (float)cols;
  float s = 2.f * mean / sqrtf(127.f);
  unsigned short* wqr = wq + (size_t)row * cols;
  for (int j = threadIdx.x; j < cols; j += blockDim.x) {
    float r = wr[j] / s;
    r = fminf(fmaxf(r, -128.f), 127.f);
    wqr[j] = f2bf(rintf(r) * s);
  }
}

// ---------- pipelined 256x256 GEMM (A: MxK rm, B: NxK rm) ----------
// Round-4 schedule (best measured) + T1 bijective XCD swizzle (y-major slabs):
// hardware round-robins flat bid across 8 XCDs; remap so each XCD owns a
// contiguous M-slab with ALL N-blocks => A-panels fetched once per XCD and
// shared in-flight in its L2 (GEMM2: 32-block chunk = 8 M-slabs x 4 N = one
// CU-round; GEMM1: 8 A-panels = 4MB = L2-resident across the XCD's rounds).
#define BAR() __builtin_amdgcn_s_barrier()
#define SB() __builtin_amdgcn_sched_barrier(0)
#define LGKM(n) { asm volatile("s_waitcnt lgkmcnt(" #n ")" ::: "memory"); SB(); }
#define VMC0() { asm volatile("s_waitcnt vmcnt(0)" ::: "memory"); SB(); }
#define PRIO1() __builtin_amdgcn_s_setprio(1)
#define PRIO0() __builtin_amdgcn_s_setprio(0)

#define STG(gbase, ldsbuf, h, kt) { \
  _Pragma("unroll") for (int i_ = 0; i_ < 2; ++i_) { \
    const int rb_ = (h) * 128 + (w * 2 + i_) * 8; \
    gload_lds16((gbase) + (size_t)rb_ * K + (size_t)(kt) * 64, (void*)((ldsbuf) + rb_ * 64)); } }

#define LDA_(dst, buf, mh) { \
  _Pragma("unroll") for (int mi_ = 0; mi_ < 4; ++mi_) { \
    dst[mi_][0] = *(const short8*)((buf) + aBase + (mh) * 4096 + mi_ * 1024 + ck0); \
    dst[mi_][1] = *(const short8*)((buf) + aBase + (mh) * 4096 + mi_ * 1024 + ck1); } }

#define LDB_(dst, buf, nh) { \
  _Pragma("unroll") for (int ni_ = 0; ni_ < 2; ++ni_) { \
    dst[ni_][0] = *(const short8*)((buf) + bBase + (nh) * 2048 + ni_ * 1024 + ck0); \
    dst[ni_][1] = *(const short8*)((buf) + bBase + (nh) * 2048 + ni_ * 1024 + ck1); } }

#define MMQ(aR, bR, mh, nh) { \
  _Pragma("unroll") for (int kk_ = 0; kk_ < 2; ++kk_) \
  _Pragma("unroll") for (int mi_ = 0; mi_ < 4; ++mi_) \
  _Pragma("unroll") for (int ni_ = 0; ni_ < 2; ++ni_) \
    acc[(mh) * 4 + mi_][(nh) * 2 + ni_] = __builtin_amdgcn_mfma_f32_16x16x32_bf16( \
        aR[mi_][kk_], bR[ni_][kk_], acc[(mh) * 4 + mi_][(nh) * 2 + ni_], 0, 0, 0); }

template <int EPI>
__global__ __launch_bounds__(512, 2) void gemm_bt_pl(
    const unsigned short* __restrict__ A, const unsigned short* __restrict__ B,
    const float* __restrict__ bias, const float* __restrict__ s2,
    const float* __restrict__ beta, unsigned short* __restrict__ Cq,
    float* __restrict__ Cf, int N, int K)
{
  __shared__ __align__(16) unsigned short As0[256 * 64];
  __shared__ __align__(16) unsigned short As1[256 * 64];
  __shared__ __align__(16) unsigned short Bs0[256 * 64];
  __shared__ __align__(16) unsigned short Bs1[256 * 64];

  const int tid = threadIdx.x;
  const int w = tid >> 6, ll = tid & 63;
  const int wr = w >> 2, wc = w & 3;

  // T1: bijective XCD swizzle, y-major slab order (nwg % 8 == 0 for our grids)
  const int nwg = gridDim.x * gridDim.y;
  const int bid = blockIdx.x + gridDim.x * blockIdx.y;
  const int cpx = nwg >> 3;
  const int swz = (bid & 7) * cpx + (bid >> 3);
  const int gy = gridDim.y;
  const int bx = swz / gy, by = swz - bx * gy;   // y fastest within slab
  const long bm = (long)bx * 256;
  const long bn = (long)by * 256;

  // staging source (pre-swizzled so linear LDS dest + XOR read = consistent, rule #21)
  const int srow = ll >> 3;
  const int scol = ((ll & 7) ^ srow) << 3;
  const unsigned short* Agl = A + ((size_t)bm + srow) * K + scol;
  const unsigned short* Bgl = B + ((size_t)bn + srow) * K + scol;

  // per-lane ds_read offsets (u16 elems)
  const int lhi = ll >> 4, llo = ll & 15, l7 = ll & 7;
  const int ck0 = ((0 * 4 + lhi) ^ l7) * 8;
  const int ck1 = ((1 * 4 + lhi) ^ l7) * 8;
  const int aBase = (wr * 128 + llo) * 64;
  const int bBase = (wc * 64 + llo) * 64;

  f32x4 acc[8][4] = {};
  short8 a0[4][2], a1[4][2], b0[2][2], b1[2][2];

  const int nkt = K >> 6;   // >= 2 for all shapes here

  // ---- prologue: stage tile0 -> buf0, tile1 -> buf1; prove tile0; pre-read R1(0) ----
  STG(Agl, As0, 0, 0); STG(Agl, As0, 1, 0);
  STG(Bgl, Bs0, 0, 0); STG(Bgl, Bs0, 1, 0);
  STG(Agl, As1, 0, 1); STG(Agl, As1, 1, 1);
  STG(Bgl, Bs1, 0, 1); STG(Bgl, Bs1, 1, 1);
  asm volatile("s_waitcnt vmcnt(8)" ::: "memory"); SB();
  BAR();
  LDA_(a0, As0, 0);                 // 8 reads  (tile0 quadrant A0)
  LDB_(b0, Bs0, 0);                 // 4 reads  (tile0 quadrant B0)

  for (int t = 0; t < nkt; ++t) {
    unsigned short* Asb = (t & 1) ? As1 : As0;
    unsigned short* Bsb = (t & 1) ? Bs1 : Bs0;
    unsigned short* Asn = (t & 1) ? As0 : As1;
    unsigned short* Bsn = (t & 1) ? Bs0 : Bs1;
    const bool i1 = (t + 1 < nkt), i2 = (t + 2 < nkt);

    // entry invariant: lgkm outstanding = 12 (a0,b0 of tile t)
    LDB_(b1, Bsb, 1);                                   // +4 -> 16
    LGKM(4);                                            // a0,b0 ready; b1 in flight
    PRIO1(); MMQ(a0, b0, 0, 0); PRIO0();                // Q1
    LDA_(a1, Asb, 1);                                   // +8 -> <=12
    LGKM(8);                                            // b1 ready; a1 in flight
    PRIO1(); MMQ(a0, b1, 0, 1); PRIO0();                // Q2
    LGKM(0);                                            // a1 ready; all cur reads drained
    PRIO1(); MMQ(a1, b0, 1, 0); PRIO0();                // Q3
    VMC0();                                             // tile t+1 stages landed (per-wave)
    BAR();                                              // block-wide: t+1 proven, cur free
    if (i2) {
      STG(Agl, Asb, 0, t + 2); STG(Agl, Asb, 1, t + 2);
      STG(Bgl, Bsb, 0, t + 2); STG(Bgl, Bsb, 1, t + 2);
    }
    if (i1) {
      LDA_(a0, Asn, 0);                                 // next-tile R1 into freed regs
      LDB_(b0, Bsn, 0);
    }
    PRIO1(); MMQ(a1, b1, 1, 1); PRIO0();                // Q4 overlaps R1' drain + stage issue
  }

  // ---- epilogue; C/D layout: col = lane&15, row = (lane>>4)*4 + reg ----
  const int lr = lhi;
  const int lc = llo;
#pragma unroll
  for (int NI = 0; NI < 4; ++NI) {
    const long col = bn + wc * 64 + NI * 16 + lc;
    const float bv = bias[col];
    float sv = 1.f, bev = 0.f, inv = 1.f;
    if (EPI == 0) { sv = s2[col]; bev = beta[col]; inv = 1.0f / sv; }
#pragma unroll
    for (int MI = 0; MI < 8; ++MI) {
#pragma unroll
      for (int r = 0; r < 4; ++r) {
        const size_t rowg = (size_t)(bm + wr * 128 + MI * 16 + lr * 4 + r);
        float v = acc[MI][NI][r] + bv;
        if (EPI == 0) {
          float g = 0.5f * v * (1.f + erf_fast(v * 0.70710678118654752f));
          float rr = (g - bev) * inv;
          rr = fminf(fmaxf(rr, 0.f), 255.f);
          Cq[rowg * N + col] = f2bf(fmaf(rintf(rr), sv, bev));
        } else {
          Cf[rowg * N + col] = v;
        }
      }
    }
  }
}

// ---------- launch ----------
extern "C" void kernel_launch(void* const* d_in, const int* in_sizes, int n_in,
                              void* d_out, int out_size, void* d_ws, size_t ws_size,
                              hipStream_t stream) {
  const float* x     = (const float*)d_in[0];
  const float* w1    = (const float*)d_in[1];
  const float* b1    = (const float*)d_in[2];
  const float* w2    = (const float*)d_in[3];
  const float* b2    = (const float*)d_in[4];
  const float* s_a1  = (const float*)d_in[5];
  const float* s_a2  = (const float*)d_in[6];
  const float* beta2 = (const float*)d_in[7];
  float* out = (float*)d_out;

  const int C = 1024, H = 4096;
  const int M = in_sizes[0] / C;  // 16384

  // workspace layout (bf16 bit-patterns as u16): xq | wq1 | wq2 | hq
  unsigned short* xq  = (unsigned short*)d_ws;
  unsigned short* wq1 = xq  + (size_t)M * C;
  unsigned short* wq2 = wq1 + (size_t)H * C;
  unsigned short* hq  = wq2 + (size_t)C * H;

  quant_x_kernel<<<2048, 256, 0, stream>>>((const float4*)x, s_a1, (ushort4_t*)xq,
                                           M * C / 4, C / 4 - 1);
  quant_w_kernel<<<H, 256, 0, stream>>>(w1, wq1, C);
  quant_w_kernel<<<C, 256, 0, stream>>>(w2, wq2, H);

  dim3 g1(M / 256, H / 256);  // 64 x 16
  gemm_bt_pl<0><<<g1, 512, 0, stream>>>(xq, wq1, b1, s_a2, beta2, hq, nullptr, H, C);
  dim3 g2(M / 256, C / 256);  // 64 x 4
  gemm_bt_pl<1><<<g2, 512, 0, stream>>>(hq, wq2, b2, nullptr, nullptr, nullptr, out, C, H);
}